// Round 2
// baseline (4595.082 us; speedup 1.0000x reference)
//
#include <hip/hip_runtime.h>
#include <math.h>

#define BB 64      // batch
#define CC 64      // width/channels
#define SS 8192    // sequence
#define NMODE 256  // kept rfft modes
#define KK2 512    // 2*NMODE (re/im interleaved)

__device__ __forceinline__ float gelu_exact(float v) {
    return 0.5f * v * (1.0f + erff(v * 0.7071067811865476f));
}

// ---------------- DFT basis tables ----------------
// F[n][2k]   =  cos(2*pi*k*n/S)
// F[n][2k+1] = -sin(2*pi*k*n/S)
// FT is the transpose: FT[2k][n], FT[2k+1][n].
// Exact integer phase reduction keeps table error ~1 ulp.
__global__ void build_F(float* __restrict__ F) {
    int n = blockIdx.x;          // 0..8191
    int k = threadIdx.x;         // 0..255
    int m = (n * k) & (SS - 1);
    float th = (float)m * (6.283185307179586476925f / (float)SS);
    float s, c;
    sincosf(th, &s, &c);
    *(float2*)&F[n * KK2 + 2 * k] = make_float2(c, -s);
}

__global__ void build_FT(float* __restrict__ FT) {
    int k = blockIdx.x;                      // 0..255
    int n = blockIdx.y * 256 + threadIdx.x;  // 0..8191
    int m = (n * k) & (SS - 1);
    float th = (float)m * (6.283185307179586476925f / (float)SS);
    float s, c;
    sincosf(th, &s, &c);
    FT[(2 * k) * SS + n] = c;
    FT[(2 * k + 1) * SS + n] = -s;
}

// ---------------- lifting layer ----------------
// x[b][c][n] = u[b][n]*W0[0][c] + grid(n)*W0[1][c] + b0[c]
__global__ void lift_kernel(const float* __restrict__ u, const float* __restrict__ w0,
                            const float* __restrict__ b0, float* __restrict__ x) {
    int n = blockIdx.x * 256 + threadIdx.x;
    int c = blockIdx.y;
    int b = blockIdx.z;
    float uv = u[b * SS + n];
    float g = (float)n * (1.0f / (float)(SS - 1));
    x[(b * CC + c) * SS + n] = uv * w0[c] + g * w0[CC + c] + b0[c];
}

// ---------------- forward truncated DFT as GEMM ----------------
// Xf[4096][512] = X[4096][8192] @ F[8192][512]
__global__ __launch_bounds__(256) void dft_fwd(const float* __restrict__ X,
                                               const float* __restrict__ F,
                                               float* __restrict__ Xf) {
    __shared__ float As[16][64];  // [k][m]
    __shared__ float Bs[16][64];  // [k][n]
    int m0 = blockIdx.y * 64;
    int c0 = blockIdx.x * 64;
    int tid = threadIdx.x;
    int lr = tid >> 2, lq = tid & 3;   // A-tile load: row, k-quad
    int bk = tid >> 4, bq = tid & 15;  // B-tile load: k-row, col-quad
    int tm = tid & 15, tn = tid >> 4;  // compute micro-tile coords
    float acc[4][4] = {};
    for (int kt = 0; kt < SS; kt += 16) {
        float4 av = *(const float4*)&X[(m0 + lr) * SS + kt + lq * 4];
        float4 bv = *(const float4*)&F[(kt + bk) * KK2 + c0 + bq * 4];
        __syncthreads();
        As[lq * 4 + 0][lr] = av.x;
        As[lq * 4 + 1][lr] = av.y;
        As[lq * 4 + 2][lr] = av.z;
        As[lq * 4 + 3][lr] = av.w;
        *(float4*)&Bs[bk][bq * 4] = bv;
        __syncthreads();
#pragma unroll
        for (int kk = 0; kk < 16; kk++) {
            const float4 a4 = *(const float4*)&As[kk][tm * 4];
            const float4 b4 = *(const float4*)&Bs[kk][tn * 4];
            const float ar[4] = {a4.x, a4.y, a4.z, a4.w};
            const float br[4] = {b4.x, b4.y, b4.z, b4.w};
#pragma unroll
            for (int i = 0; i < 4; i++)
#pragma unroll
                for (int j = 0; j < 4; j++)
                    acc[i][j] = fmaf(ar[i], br[j], acc[i][j]);
        }
    }
#pragma unroll
    for (int i = 0; i < 4; i++) {
        *(float4*)&Xf[(m0 + tm * 4 + i) * KK2 + c0 + tn * 4] =
            make_float4(acc[i][0], acc[i][1], acc[i][2], acc[i][3]);
    }
}

// ---------------- mode mixing (complex, per-k channel GEMM) ----------------
// om[b,o,k] = c_k * sum_i Xf[b,i,k] * (wr + i*wi)[l,i,o,k]
__global__ __launch_bounds__(256) void mode_mix(const float* __restrict__ Xf,
                                                const float* __restrict__ swr,
                                                const float* __restrict__ swi,
                                                float* __restrict__ om, int l) {
    int k = threadIdx.x;       // 0..255
    int bg = blockIdx.x * 4;   // batch group
    int og = blockIdx.y * 4;   // out-channel group
    float accr[4][4] = {}, acci[4][4] = {};
    for (int i = 0; i < CC; i++) {
        float xr[4], xi[4], wr[4], wi[4];
#pragma unroll
        for (int t = 0; t < 4; t++) {
            float2 v = *(const float2*)&Xf[((bg + t) * CC + i) * KK2 + 2 * k];
            xr[t] = v.x;
            xi[t] = v.y;
        }
#pragma unroll
        for (int t = 0; t < 4; t++) {
            size_t wbase = ((size_t)(l * CC + i) * CC + (og + t)) * NMODE + k;
            wr[t] = swr[wbase];
            wi[t] = swi[wbase];
        }
#pragma unroll
        for (int b2 = 0; b2 < 4; b2++)
#pragma unroll
            for (int oo = 0; oo < 4; oo++) {
                accr[b2][oo] += xr[b2] * wr[oo] - xi[b2] * wi[oo];
                acci[b2][oo] += xr[b2] * wi[oo] + xi[b2] * wr[oo];
            }
    }
    float ck = (k == 0) ? (1.0f / (float)SS) : (2.0f / (float)SS);
#pragma unroll
    for (int b2 = 0; b2 < 4; b2++)
#pragma unroll
        for (int oo = 0; oo < 4; oo++) {
            *(float2*)&om[((bg + b2) * CC + og + oo) * KK2 + 2 * k] =
                make_float2(accr[b2][oo] * ck, acci[b2][oo] * ck);
        }
}

// ---------------- inverse DFT + pointwise conv + bias + gelu, in place -------
// y[b,o,n] = sum_k2 om[b*64+o,k2]*FT[k2,n] + sum_i pw[l,o,i]*x[b,i,n] + pwb[l,o]
// Treated as one GEMM with K = 512 (modes) + 64 (channels). Each block owns
// (b, n-tile) exclusively, so the in-place update of x is race-free.
__global__ __launch_bounds__(256) void inv_pw(const float* __restrict__ om,
                                              const float* __restrict__ FT,
                                              const float* __restrict__ pww,
                                              const float* __restrict__ pwb,
                                              float* __restrict__ x, int l,
                                              int apply_gelu) {
    __shared__ float As[16][64];
    __shared__ float Bs[16][64];
    int b = blockIdx.y;
    int n0 = blockIdx.x * 64;
    int tid = threadIdx.x;
    int lr = tid >> 2, lq = tid & 3;
    int bk = tid >> 4, bq = tid & 15;
    int tm = tid & 15, tn = tid >> 4;
    float acc[4][4] = {};
    // phase 1: modes (K = 512)
    for (int kt = 0; kt < KK2; kt += 16) {
        float4 av = *(const float4*)&om[(b * CC + lr) * KK2 + kt + lq * 4];
        float4 bv = *(const float4*)&FT[(kt + bk) * SS + n0 + bq * 4];
        __syncthreads();
        As[lq * 4 + 0][lr] = av.x;
        As[lq * 4 + 1][lr] = av.y;
        As[lq * 4 + 2][lr] = av.z;
        As[lq * 4 + 3][lr] = av.w;
        *(float4*)&Bs[bk][bq * 4] = bv;
        __syncthreads();
#pragma unroll
        for (int kk = 0; kk < 16; kk++) {
            const float4 a4 = *(const float4*)&As[kk][tm * 4];
            const float4 b4 = *(const float4*)&Bs[kk][tn * 4];
            const float ar[4] = {a4.x, a4.y, a4.z, a4.w};
            const float br[4] = {b4.x, b4.y, b4.z, b4.w};
#pragma unroll
            for (int i = 0; i < 4; i++)
#pragma unroll
                for (int j = 0; j < 4; j++)
                    acc[i][j] = fmaf(ar[i], br[j], acc[i][j]);
        }
    }
    // phase 2: pointwise conv (K = 64 input channels)
    for (int it = 0; it < CC; it += 16) {
        float4 av = *(const float4*)&pww[(l * CC + lr) * CC + it + lq * 4];
        float4 bv = *(const float4*)&x[(b * CC + it + bk) * SS + n0 + bq * 4];
        __syncthreads();
        As[lq * 4 + 0][lr] = av.x;
        As[lq * 4 + 1][lr] = av.y;
        As[lq * 4 + 2][lr] = av.z;
        As[lq * 4 + 3][lr] = av.w;
        *(float4*)&Bs[bk][bq * 4] = bv;
        __syncthreads();
#pragma unroll
        for (int kk = 0; kk < 16; kk++) {
            const float4 a4 = *(const float4*)&As[kk][tm * 4];
            const float4 b4 = *(const float4*)&Bs[kk][tn * 4];
            const float ar[4] = {a4.x, a4.y, a4.z, a4.w};
            const float br[4] = {b4.x, b4.y, b4.z, b4.w};
#pragma unroll
            for (int i = 0; i < 4; i++)
#pragma unroll
                for (int j = 0; j < 4; j++)
                    acc[i][j] = fmaf(ar[i], br[j], acc[i][j]);
        }
    }
    // epilogue: bias (+ gelu), in-place store (all global x reads done above)
#pragma unroll
    for (int i = 0; i < 4; i++) {
        int o = tm * 4 + i;
        float bias = pwb[l * CC + o];
        float v0 = acc[i][0] + bias;
        float v1 = acc[i][1] + bias;
        float v2 = acc[i][2] + bias;
        float v3 = acc[i][3] + bias;
        if (apply_gelu) {
            v0 = gelu_exact(v0);
            v1 = gelu_exact(v1);
            v2 = gelu_exact(v2);
            v3 = gelu_exact(v3);
        }
        *(float4*)&x[(b * CC + o) * SS + n0 + tn * 4] = make_float4(v0, v1, v2, v3);
    }
}

// ---------------- projection head ----------------
// out[b,n] = gelu(x[b,:,n] @ W1 + b1) @ W2 + b2
__global__ __launch_bounds__(256) void head_kernel(const float* __restrict__ x,
                                                   const float* __restrict__ w1,
                                                   const float* __restrict__ b1,
                                                   const float* __restrict__ w2,
                                                   const float* __restrict__ b2,
                                                   float* __restrict__ out) {
    __shared__ float Xs[64][64];
    __shared__ float W1s[64][128];
    __shared__ float part[4][64];
    int b = blockIdx.y;
    int n0 = blockIdx.x * 64;
    int tid = threadIdx.x;
    {
        // 4 threads per row (nq), each loads 16 floats -> full 64 columns
        int c = tid >> 2, nq = tid & 3;
#pragma unroll
        for (int q = 0; q < 4; q++) {
            int col = nq * 16 + q * 4;
            *(float4*)&Xs[c][col] = *(const float4*)&x[(b * CC + c) * SS + n0 + col];
        }
    }
    float* w1flat = &W1s[0][0];
#pragma unroll
    for (int q = 0; q < 8; q++) {
        int off = q * 1024 + tid * 4;
        *(float4*)&w1flat[off] = *(const float4*)&w1[off];
    }
    __syncthreads();
    int nn = tid & 63, jg = tid >> 6;
    float h[32];
#pragma unroll
    for (int jj = 0; jj < 32; jj++) h[jj] = b1[jg * 32 + jj];
    for (int c = 0; c < 64; c++) {
        float xv = Xs[c][nn];
#pragma unroll
        for (int jj = 0; jj < 32; jj++)
            h[jj] = fmaf(xv, W1s[c][jg * 32 + jj], h[jj]);
    }
    float p = 0.f;
#pragma unroll
    for (int jj = 0; jj < 32; jj++)
        p = fmaf(gelu_exact(h[jj]), w2[jg * 32 + jj], p);
    part[jg][nn] = p;
    __syncthreads();
    if (tid < 64) {
        float v = part[0][tid] + part[1][tid] + part[2][tid] + part[3][tid] + b2[0];
        out[b * SS + n0 + tid] = v;
    }
}

extern "C" void kernel_launch(void* const* d_in, const int* in_sizes, int n_in,
                              void* d_out, int out_size, void* d_ws, size_t ws_size,
                              hipStream_t stream) {
    (void)in_sizes; (void)n_in; (void)out_size; (void)ws_size;
    const float* u = (const float*)d_in[0];
    const float* fc0_w = (const float*)d_in[1];
    const float* fc0_b = (const float*)d_in[2];
    const float* sw_r = (const float*)d_in[3];
    const float* sw_i = (const float*)d_in[4];
    const float* pw_w = (const float*)d_in[5];
    const float* pw_b = (const float*)d_in[6];
    const float* fc1_w = (const float*)d_in[7];
    const float* fc1_b = (const float*)d_in[8];
    const float* fc2_w = (const float*)d_in[9];
    const float* fc2_b = (const float*)d_in[10];
    float* out = (float*)d_out;

    float* ws = (float*)d_ws;
    float* x = ws;                              // 64*64*8192      = 33,554,432 f
    float* F = x + (size_t)BB * CC * SS;        // 8192*512        =  4,194,304 f
    float* FT = F + (size_t)SS * KK2;           // 512*8192        =  4,194,304 f
    float* Xf = FT + (size_t)SS * KK2;          // 4096*512        =  2,097,152 f
    float* om = Xf + (size_t)(BB * CC) * KK2;   // 4096*512        =  2,097,152 f
    // total ws: 184,549,376 bytes

    build_F<<<dim3(SS), 256, 0, stream>>>(F);
    build_FT<<<dim3(NMODE, SS / 256), 256, 0, stream>>>(FT);
    lift_kernel<<<dim3(SS / 256, CC, BB), 256, 0, stream>>>(u, fc0_w, fc0_b, x);

    for (int l = 0; l < 4; l++) {
        dft_fwd<<<dim3(KK2 / 64, (BB * CC) / 64), 256, 0, stream>>>(x, F, Xf);
        mode_mix<<<dim3(BB / 4, CC / 4), 256, 0, stream>>>(Xf, sw_r, sw_i, om, l);
        inv_pw<<<dim3(SS / 64, BB), 256, 0, stream>>>(om, FT, pw_w, pw_b, x, l,
                                                      (l < 3) ? 1 : 0);
    }
    head_kernel<<<dim3(SS / 64, BB), 256, 0, stream>>>(x, fc1_w, fc1_b, fc2_w,
                                                       fc2_b, out);
}

// Round 3
// 1731.053 us; speedup vs baseline: 2.6545x; 2.6545x over previous
//
#include <hip/hip_runtime.h>
#include <hip/hip_bf16.h>
#include <math.h>

#define BB 64      // batch
#define CC 64      // width/channels
#define SS 8192    // sequence
#define NMODE 256  // kept rfft modes
#define KK2 512    // 2*NMODE (re/im interleaved)

typedef __attribute__((ext_vector_type(8))) short short8;
typedef __attribute__((ext_vector_type(4))) float f32x4;

__device__ __forceinline__ float gelu_exact(float v) {
    return 0.5f * v * (1.0f + erff(v * 0.7071067811865476f));
}

__device__ __forceinline__ float b2f(ushort u) {
    return __uint_as_float(((unsigned int)u) << 16);
}
__device__ __forceinline__ ushort f2b(float v) {
    __hip_bfloat16 h = __float2bfloat16(v);  // RNE
    return *(ushort*)&h;
}
__device__ __forceinline__ void split2(float v, ushort& h, ushort& l) {
    h = f2b(v);
    l = f2b(v - b2f(h));
}

// ---------------- DFT basis tables (bf16 hi/lo pairs) ----------------
// T1[c][n] (c = 2k+ri over 512, n over 8192): dft B operand (contiguous n).
// T2[n][c]: inv B operand (contiguous c). Values: ri==0 ? cos : -sin of 2πkn/S.
__global__ void build_T1(ushort* __restrict__ h, ushort* __restrict__ l) {
    int c = blockIdx.x;
    int n = blockIdx.y * 256 + threadIdx.x;
    int k = c >> 1;
    int m = (n * k) & (SS - 1);
    float th = (float)m * (6.283185307179586476925f / (float)SS);
    float s, co;
    sincosf(th, &s, &co);
    float v = (c & 1) ? -s : co;
    ushort hh, ll;
    split2(v, hh, ll);
    h[(size_t)c * SS + n] = hh;
    l[(size_t)c * SS + n] = ll;
}

__global__ void build_T2(ushort* __restrict__ h, ushort* __restrict__ l) {
    int n = blockIdx.x;
    int c = blockIdx.y * 256 + threadIdx.x;
    int k = c >> 1;
    int m = (n * k) & (SS - 1);
    float th = (float)m * (6.283185307179586476925f / (float)SS);
    float s, co;
    sincosf(th, &s, &co);
    float v = (c & 1) ? -s : co;
    ushort hh, ll;
    split2(v, hh, ll);
    h[(size_t)n * KK2 + c] = hh;
    l[(size_t)n * KK2 + c] = ll;
}

__global__ void zero_xf(float* __restrict__ p) {
    size_t i = ((size_t)blockIdx.x * 256 + threadIdx.x) * 4;
    *(float4*)&p[i] = make_float4(0.f, 0.f, 0.f, 0.f);
}

// ---------------- lifting layer (writes split x) ----------------
__global__ void lift_kernel(const float* __restrict__ u, const float* __restrict__ w0,
                            const float* __restrict__ b0, ushort* __restrict__ xh,
                            ushort* __restrict__ xl) {
    int n = blockIdx.x * 256 + threadIdx.x;
    int c = blockIdx.y;
    int b = blockIdx.z;
    float uv = u[b * SS + n];
    float g = (float)n * (1.0f / (float)(SS - 1));
    float v = uv * w0[c] + g * w0[CC + c] + b0[c];
    ushort hh, ll;
    split2(v, hh, ll);
    size_t idx = (size_t)(b * CC + c) * SS + n;
    xh[idx] = hh;
    xl[idx] = ll;
}

// ---------------- forward truncated DFT: split-bf16 MFMA GEMM ----------------
// Xf[m=bc 4096][c 512] += X[m][n] * T1[c][n]  (K = n = 8192, ksplit via blockIdx.z)
__global__ __launch_bounds__(256) void dft_mfma(const ushort* __restrict__ xh,
                                                const ushort* __restrict__ xl,
                                                const ushort* __restrict__ t1h,
                                                const ushort* __restrict__ t1l,
                                                float* __restrict__ Xf) {
    __shared__ __align__(16) ushort As_h[128 * 40], As_l[128 * 40];
    __shared__ __align__(16) ushort Bs_h[128 * 40], Bs_l[128 * 40];
    const int t = threadIdx.x;
    const int c0 = blockIdx.x * 128;
    const int m0 = blockIdx.y * 128;
    const int kz = blockIdx.z * 2048;
    const int lane = t & 63, w = t >> 6;
    const int wm = (w >> 1) * 64, wn = (w & 1) * 64;
    const int fr = lane & 15, q8 = (lane >> 4) * 8;
    const int sr = t >> 1, sh = (t & 1) * 16;  // staging: 2 thr/row, 16 els each

    f32x4 acc[4][4];
#pragma unroll
    for (int i = 0; i < 4; i++)
#pragma unroll
        for (int j = 0; j < 4; j++) acc[i][j] = (f32x4)0.f;

    for (int kt = kz; kt < kz + 2048; kt += 32) {
        const size_t ga = (size_t)(m0 + sr) * SS + kt + sh;
        short8 a0h = *(const short8*)&xh[ga];
        short8 a1h = *(const short8*)&xh[ga + 8];
        short8 a0l = *(const short8*)&xl[ga];
        short8 a1l = *(const short8*)&xl[ga + 8];
        const size_t gb = (size_t)(c0 + sr) * SS + kt + sh;
        short8 b0h = *(const short8*)&t1h[gb];
        short8 b1h = *(const short8*)&t1h[gb + 8];
        short8 b0l = *(const short8*)&t1l[gb];
        short8 b1l = *(const short8*)&t1l[gb + 8];
        __syncthreads();
        {
            ushort* d = &As_h[sr * 40 + sh];
            *(short8*)d = a0h;
            *(short8*)(d + 8) = a1h;
            d = &As_l[sr * 40 + sh];
            *(short8*)d = a0l;
            *(short8*)(d + 8) = a1l;
            d = &Bs_h[sr * 40 + sh];
            *(short8*)d = b0h;
            *(short8*)(d + 8) = b1h;
            d = &Bs_l[sr * 40 + sh];
            *(short8*)d = b0l;
            *(short8*)(d + 8) = b1l;
        }
        __syncthreads();
        short8 ah[4], al[4];
#pragma unroll
        for (int mt = 0; mt < 4; mt++) {
            int off = (wm + mt * 16 + fr) * 40 + q8;
            ah[mt] = *(const short8*)&As_h[off];
            al[mt] = *(const short8*)&As_l[off];
        }
#pragma unroll
        for (int nt = 0; nt < 4; nt++) {
            int off = (wn + nt * 16 + fr) * 40 + q8;
            short8 bh = *(const short8*)&Bs_h[off];
            short8 bl = *(const short8*)&Bs_l[off];
#pragma unroll
            for (int mt = 0; mt < 4; mt++) {
                acc[mt][nt] = __builtin_amdgcn_mfma_f32_16x16x32_bf16(ah[mt], bh, acc[mt][nt], 0, 0, 0);
                acc[mt][nt] = __builtin_amdgcn_mfma_f32_16x16x32_bf16(ah[mt], bl, acc[mt][nt], 0, 0, 0);
                acc[mt][nt] = __builtin_amdgcn_mfma_f32_16x16x32_bf16(al[mt], bh, acc[mt][nt], 0, 0, 0);
            }
        }
    }
    const int rr = (lane >> 4) * 4;
#pragma unroll
    for (int mt = 0; mt < 4; mt++) {
        int m = m0 + wm + mt * 16 + rr;
#pragma unroll
        for (int nt = 0; nt < 4; nt++) {
            int c = c0 + wn + nt * 16 + fr;
#pragma unroll
            for (int r = 0; r < 4; r++)
                atomicAdd(&Xf[(size_t)(m + r) * KK2 + c], acc[mt][nt][r]);
        }
    }
}

// ---------------- mode mixing (fp32, writes split om) ----------------
__global__ __launch_bounds__(256) void mode_mix(const float* __restrict__ Xf,
                                                const float* __restrict__ swr,
                                                const float* __restrict__ swi,
                                                ushort* __restrict__ omh,
                                                ushort* __restrict__ oml, int l) {
    int k = threadIdx.x;
    int bg = blockIdx.x * 4;
    int og = blockIdx.y * 4;
    float accr[4][4] = {}, acci[4][4] = {};
    for (int i = 0; i < CC; i++) {
        float xr[4], xi[4], wr[4], wi[4];
#pragma unroll
        for (int t = 0; t < 4; t++) {
            float2 v = *(const float2*)&Xf[((size_t)(bg + t) * CC + i) * KK2 + 2 * k];
            xr[t] = v.x;
            xi[t] = v.y;
        }
#pragma unroll
        for (int t = 0; t < 4; t++) {
            size_t wbase = ((size_t)(l * CC + i) * CC + (og + t)) * NMODE + k;
            wr[t] = swr[wbase];
            wi[t] = swi[wbase];
        }
#pragma unroll
        for (int b2 = 0; b2 < 4; b2++)
#pragma unroll
            for (int oo = 0; oo < 4; oo++) {
                accr[b2][oo] += xr[b2] * wr[oo] - xi[b2] * wi[oo];
                acci[b2][oo] += xr[b2] * wi[oo] + xi[b2] * wr[oo];
            }
    }
    float ck = (k == 0) ? (1.0f / (float)SS) : (2.0f / (float)SS);
#pragma unroll
    for (int b2 = 0; b2 < 4; b2++)
#pragma unroll
        for (int oo = 0; oo < 4; oo++) {
            float re = accr[b2][oo] * ck;
            float im = acci[b2][oo] * ck;
            ushort hr, lr2, hi2, li2;
            split2(re, hr, lr2);
            split2(im, hi2, li2);
            size_t base = ((size_t)(bg + b2) * CC + og + oo) * KK2 + 2 * k;
            *(ushort2*)&omh[base] = make_ushort2(hr, hi2);
            *(ushort2*)&oml[base] = make_ushort2(lr2, li2);
        }
}

// ---------------- inverse DFT + pointwise + bias + gelu (MFMA, in place) ----
// Block: rows row0..row0+127 (= 2 batches x 64 out-ch), cols n0..n0+127.
// Phase 1 (s<16): K=512 modes, A=om pairs, B=T2. Phase 2 (s=16,17): K=64
// channels, A=pw (split on the fly), B=x channels transposed into LDS.
__global__ __launch_bounds__(256) void inv_mfma(const ushort* __restrict__ omh,
                                                const ushort* __restrict__ oml,
                                                const ushort* __restrict__ t2h,
                                                const ushort* __restrict__ t2l,
                                                const float* __restrict__ pww,
                                                const float* __restrict__ pwb,
                                                ushort* __restrict__ xh,
                                                ushort* __restrict__ xl, int l,
                                                int gel) {
    __shared__ __align__(16) ushort As_h[128 * 40], As_l[128 * 40];
    __shared__ __align__(16) ushort Bs_h[2 * 128 * 40], Bs_l[2 * 128 * 40];
    const int t = threadIdx.x;
    const int n0 = blockIdx.x * 128;
    const int row0 = blockIdx.y * 128;
    const int lane = t & 63, w = t >> 6;
    const int wm = (w >> 1) * 64, wn = (w & 1) * 64;
    const int bsw = w >> 1;  // which batch-sub this wave's rows belong to
    const int fr = lane & 15, q8 = (lane >> 4) * 8;
    const int sr = t >> 1, sh = (t & 1) * 16;

    f32x4 acc[4][4];
#pragma unroll
    for (int i = 0; i < 4; i++)
#pragma unroll
        for (int j = 0; j < 4; j++) acc[i][j] = (f32x4)0.f;

    for (int s = 0; s < 18; s++) {
        int boff;
        if (s < 16) {
            boff = 0;
            int k2 = s * 32;
            size_t ga = (size_t)(row0 + sr) * KK2 + k2 + sh;
            short8 a0h = *(const short8*)&omh[ga];
            short8 a1h = *(const short8*)&omh[ga + 8];
            short8 a0l = *(const short8*)&oml[ga];
            short8 a1l = *(const short8*)&oml[ga + 8];
            size_t gb = (size_t)(n0 + sr) * KK2 + k2 + sh;
            short8 b0h = *(const short8*)&t2h[gb];
            short8 b1h = *(const short8*)&t2h[gb + 8];
            short8 b0l = *(const short8*)&t2l[gb];
            short8 b1l = *(const short8*)&t2l[gb + 8];
            __syncthreads();
            ushort* d = &As_h[sr * 40 + sh];
            *(short8*)d = a0h;
            *(short8*)(d + 8) = a1h;
            d = &As_l[sr * 40 + sh];
            *(short8*)d = a0l;
            *(short8*)(d + 8) = a1l;
            d = &Bs_h[sr * 40 + sh];
            *(short8*)d = b0h;
            *(short8*)(d + 8) = b1h;
            d = &Bs_l[sr * 40 + sh];
            *(short8*)d = b0l;
            *(short8*)(d + 8) = b1l;
            __syncthreads();
        } else {
            int i0 = (s - 16) * 32;
            // A: pw weights, duplicated for both batch-subs, split on the fly
            float4 p[4];
            size_t pidx = (size_t)(l * 64 + (sr & 63)) * 64 + i0 + sh;
#pragma unroll
            for (int u2 = 0; u2 < 4; u2++) p[u2] = *(const float4*)&pww[pidx + u2 * 4];
            // B: x channels, transpose-scattered.  t = bs2(1b) | ii(5b) | sg(2b)
            int bs2 = t >> 7;
            int ii = (t >> 2) & 31;
            int sg = (t & 3) * 32;
            size_t gx = (size_t)(row0 + bs2 * 64 + i0 + ii) * SS + n0 + sg;
            short8 vh[4], vl[4];
#pragma unroll
            for (int j = 0; j < 4; j++) {
                vh[j] = *(const short8*)&xh[gx + j * 8];
                vl[j] = *(const short8*)&xl[gx + j * 8];
            }
            __syncthreads();
#pragma unroll
            for (int u2 = 0; u2 < 4; u2++) {
                float vv[4] = {p[u2].x, p[u2].y, p[u2].z, p[u2].w};
#pragma unroll
                for (int e = 0; e < 4; e++) {
                    ushort hh, ll2;
                    split2(vv[e], hh, ll2);
                    As_h[sr * 40 + sh + u2 * 4 + e] = hh;
                    As_l[sr * 40 + sh + u2 * 4 + e] = ll2;
                }
            }
#pragma unroll
            for (int j = 0; j < 4; j++)
#pragma unroll
                for (int e = 0; e < 8; e++) {
                    int nl = sg + j * 8 + e;
                    Bs_h[bs2 * 5120 + nl * 40 + ii] = (ushort)vh[j][e];
                    Bs_l[bs2 * 5120 + nl * 40 + ii] = (ushort)vl[j][e];
                }
            __syncthreads();
            boff = bsw * 5120;
        }
        short8 ah[4], al[4];
#pragma unroll
        for (int mt = 0; mt < 4; mt++) {
            int off = (wm + mt * 16 + fr) * 40 + q8;
            ah[mt] = *(const short8*)&As_h[off];
            al[mt] = *(const short8*)&As_l[off];
        }
#pragma unroll
        for (int nt = 0; nt < 4; nt++) {
            int off = boff + (wn + nt * 16 + fr) * 40 + q8;
            short8 bh = *(const short8*)&Bs_h[off];
            short8 bl = *(const short8*)&Bs_l[off];
#pragma unroll
            for (int mt = 0; mt < 4; mt++) {
                acc[mt][nt] = __builtin_amdgcn_mfma_f32_16x16x32_bf16(ah[mt], bh, acc[mt][nt], 0, 0, 0);
                acc[mt][nt] = __builtin_amdgcn_mfma_f32_16x16x32_bf16(ah[mt], bl, acc[mt][nt], 0, 0, 0);
                acc[mt][nt] = __builtin_amdgcn_mfma_f32_16x16x32_bf16(al[mt], bh, acc[mt][nt], 0, 0, 0);
            }
        }
    }
    // epilogue: bias + gelu + split-store (in place; block owns its rows/cols)
    const int rr = (lane >> 4) * 4;
#pragma unroll
    for (int mt = 0; mt < 4; mt++) {
        int rl = wm + mt * 16 + rr;
#pragma unroll
        for (int r = 0; r < 4; r++) {
            int o = (rl + r) & 63;
            float bias = pwb[l * 64 + o];
#pragma unroll
            for (int nt = 0; nt < 4; nt++) {
                int n = n0 + wn + nt * 16 + fr;
                float v = acc[mt][nt][r] + bias;
                if (gel) v = gelu_exact(v);
                ushort hh, ll2;
                split2(v, hh, ll2);
                size_t g = (size_t)(row0 + rl + r) * SS + n;
                xh[g] = hh;
                xl[g] = ll2;
            }
        }
    }
}

// ---------------- projection head ----------------
__global__ __launch_bounds__(256) void head_kernel(const ushort* __restrict__ xh,
                                                   const ushort* __restrict__ xl,
                                                   const float* __restrict__ w1,
                                                   const float* __restrict__ b1,
                                                   const float* __restrict__ w2,
                                                   const float* __restrict__ b2,
                                                   float* __restrict__ out) {
    __shared__ float Xs[64][64];
    __shared__ float W1s[64][128];
    __shared__ float part[4][64];
    int b = blockIdx.y;
    int n0 = blockIdx.x * 64;
    int tid = threadIdx.x;
    {
        int c = tid >> 2, nq = tid & 3;
        size_t gx = (size_t)(b * CC + c) * SS + n0 + nq * 16;
        short8 hA = *(const short8*)&xh[gx];
        short8 hB = *(const short8*)&xh[gx + 8];
        short8 lA = *(const short8*)&xl[gx];
        short8 lB = *(const short8*)&xl[gx + 8];
#pragma unroll
        for (int e = 0; e < 8; e++) {
            Xs[c][nq * 16 + e] = b2f((ushort)hA[e]) + b2f((ushort)lA[e]);
            Xs[c][nq * 16 + 8 + e] = b2f((ushort)hB[e]) + b2f((ushort)lB[e]);
        }
    }
    float* w1flat = &W1s[0][0];
#pragma unroll
    for (int q = 0; q < 8; q++) {
        int off = q * 1024 + tid * 4;
        *(float4*)&w1flat[off] = *(const float4*)&w1[off];
    }
    __syncthreads();
    int nn = tid & 63, jg = tid >> 6;
    float h[32];
#pragma unroll
    for (int jj = 0; jj < 32; jj++) h[jj] = b1[jg * 32 + jj];
    for (int c = 0; c < 64; c++) {
        float xv = Xs[c][nn];
#pragma unroll
        for (int jj = 0; jj < 32; jj++)
            h[jj] = fmaf(xv, W1s[c][jg * 32 + jj], h[jj]);
    }
    float p = 0.f;
#pragma unroll
    for (int jj = 0; jj < 32; jj++)
        p = fmaf(gelu_exact(h[jj]), w2[jg * 32 + jj], p);
    part[jg][nn] = p;
    __syncthreads();
    if (tid < 64) {
        float v = part[0][tid] + part[1][tid] + part[2][tid] + part[3][tid] + b2[0];
        out[b * SS + n0 + tid] = v;
    }
}

extern "C" void kernel_launch(void* const* d_in, const int* in_sizes, int n_in,
                              void* d_out, int out_size, void* d_ws, size_t ws_size,
                              hipStream_t stream) {
    (void)in_sizes; (void)n_in; (void)out_size; (void)ws_size;
    const float* u = (const float*)d_in[0];
    const float* fc0_w = (const float*)d_in[1];
    const float* fc0_b = (const float*)d_in[2];
    const float* sw_r = (const float*)d_in[3];
    const float* sw_i = (const float*)d_in[4];
    const float* pw_w = (const float*)d_in[5];
    const float* pw_b = (const float*)d_in[6];
    const float* fc1_w = (const float*)d_in[7];
    const float* fc1_b = (const float*)d_in[8];
    const float* fc2_w = (const float*)d_in[9];
    const float* fc2_b = (const float*)d_in[10];
    float* out = (float*)d_out;

    // workspace layout (total = 184,549,376 B, same as the round-1 footprint)
    char* ws = (char*)d_ws;
    ushort* xh = (ushort*)ws;                        // 33,554,432 els
    ushort* xl = (ushort*)(ws + 67108864);           // 33,554,432
    ushort* t1h = (ushort*)(ws + 134217728);         // [512][8192]
    ushort* t1l = (ushort*)(ws + 142606336);
    ushort* t2h = (ushort*)(ws + 150994944);         // [8192][512]
    ushort* t2l = (ushort*)(ws + 159383552);
    ushort* omh = (ushort*)(ws + 167772160);         // [4096][512]
    ushort* oml = (ushort*)(ws + 171966464);
    float* Xf = (float*)(ws + 176160768);            // [4096][512] fp32

    build_T1<<<dim3(KK2, SS / 256), 256, 0, stream>>>(t1h, t1l);
    build_T2<<<dim3(SS, KK2 / 256), 256, 0, stream>>>(t2h, t2l);
    lift_kernel<<<dim3(SS / 256, CC, BB), 256, 0, stream>>>(u, fc0_w, fc0_b, xh, xl);

    for (int l = 0; l < 4; l++) {
        zero_xf<<<dim3(2048), 256, 0, stream>>>(Xf);
        dft_mfma<<<dim3(KK2 / 128, (BB * CC) / 128, 4), 256, 0, stream>>>(
            xh, xl, t1h, t1l, Xf);
        mode_mix<<<dim3(BB / 4, CC / 4), 256, 0, stream>>>(Xf, sw_r, sw_i, omh, oml, l);
        inv_mfma<<<dim3(SS / 128, BB / 2), 256, 0, stream>>>(
            omh, oml, t2h, t2l, pw_w, pw_b, xh, xl, l, (l < 3) ? 1 : 0);
    }
    head_kernel<<<dim3(SS / 64, BB), 256, 0, stream>>>(xh, xl, fc1_w, fc1_b, fc2_w,
                                                       fc2_b, out);
}